// Round 19
// baseline (63.503 us; speedup 1.0000x reference)
//
#include <hip/hip_runtime.h>
#include <hip/hip_bf16.h>

#define S 512
#define HD 384
#define NPAIR 131328   // S*(S+1)/2
#define NOUT 14

typedef __bf16 bf16x8 __attribute__((ext_vector_type(8)));
typedef __bf16 bf16x4 __attribute__((ext_vector_type(4)));
typedef float f32x4 __attribute__((ext_vector_type(4)));
typedef float f32x2 __attribute__((ext_vector_type(2)));

__device__ __forceinline__ f32x4 splat4(float v) { return f32x4{v, v, v, v}; }

// ---- packed f32 (VOP3P) helpers: 2 IEEE ops per instruction, bit-identical
__device__ __forceinline__ f32x2 pk_add(f32x2 a, f32x2 b) {
  f32x2 d;
  asm("v_pk_add_f32 %0, %1, %2" : "=v"(d) : "v"(a), "v"(b));
  return d;
}
__device__ __forceinline__ f32x2 pk_mul(f32x2 a, f32x2 b) {
  f32x2 d;
  asm("v_pk_mul_f32 %0, %1, %2" : "=v"(d) : "v"(a), "v"(b));
  return d;
}
__device__ __forceinline__ f32x2 pk_fma(f32x2 a, f32x2 b, f32x2 c) {
  f32x2 d;
  asm("v_pk_fma_f32 %0, %1, %2, %3" : "=v"(d) : "v"(a), "v"(b), "v"(c));
  return d;
}

// tanh(l+r), deg-5 odd fit (same coeffs/order as R11 -> bit-identical),
// issued as packed-f32 pairs: 10 VOP3P per 4 elems.
__device__ __forceinline__ f32x4 tanh4_pk(f32x4 l, f32x4 r) {
  const f32x2 C3 = {0.065750f, 0.065750f};
  const f32x2 C2 = {-0.303330f, -0.303330f};
  const f32x2 C1 = {0.997245f, 0.997245f};
  f32x2 x0 = pk_add(f32x2{l[0], l[1]}, f32x2{r[0], r[1]});
  f32x2 x1 = pk_add(f32x2{l[2], l[3]}, f32x2{r[2], r[3]});
  f32x2 u0 = pk_mul(x0, x0), u1 = pk_mul(x1, x1);
  f32x2 p0 = pk_fma(u0, C3, C2), p1 = pk_fma(u1, C3, C2);
  p0 = pk_fma(u0, p0, C1);  p1 = pk_fma(u1, p1, C1);
  f32x2 t0 = pk_mul(x0, p0), t1 = pk_mul(x1, p1);
  return f32x4{t0[0], t0[1], t1[0], t1[1]};
}

// ---------- transpose tile helper (aliased LDS scratch) ---------------------
__device__ __forceinline__ void transp_tile_dev(
    float (*t)[33],
    const float* __restrict__ src, __bf16* __restrict__ dst,
    int R, int C, int bx, int by)
{
  const int tx = threadIdx.x & 31, ty = threadIdx.x >> 5;  // 32 x 8
  const int c = bx * 32 + tx;
  #pragma unroll
  for (int p = 0; p < 4; ++p) {
    int r = by * 32 + ty + p * 8;
    t[ty + p * 8][tx] = src[(size_t)r * C + c];
  }
  __syncthreads();
  #pragma unroll
  for (int p = 0; p < 4; ++p) {
    int cc = bx * 32 + ty + p * 8;
    int rr = by * 32 + tx;
    dst[(size_t)cc * R + rr] = (__bf16)t[tx][ty + p * 8];
  }
}

// ---------- gemm1 (TRANSP_B from raw w1) + rest-of-prep in spare blocks -----
// blocks 0..767    : h1 = relu(seq @ w1 + b1), BM=16 BN=64 BK=128,
//                    B staged transposed straight from w1 f32 (same cast/k-order
//                    as the old prep+gemm path -> bit-identical output).
// blocks 768..1055 : w2t transpose (verbatim prep logic)
// blocks 1056..1343: Wct transpose (cw top/bot)
__global__ __launch_bounds__(256) void gemm1_prep_kernel(
    const float* __restrict__ seq, const float* __restrict__ w1,
    const float* __restrict__ b1, __bf16* __restrict__ h1b,
    const float* __restrict__ w2, __bf16* __restrict__ w2t,
    const float* __restrict__ cw, __bf16* __restrict__ Wct)
{
  __shared__ __align__(16) __bf16 As[2][16][136];   //  8.7 KB
  __shared__ __align__(16) __bf16 Bs[2][64][136];   // 34.8 KB
  const int bid = blockIdx.x;
  const int tid = threadIdx.x;

  if (bid >= 768) {                      // ---- prep blocks
    float (*Ts)[33] = (float(*)[33])&As[0][0][0];   // 4.2 KB scratch
    int idx = bid - 768;
    if (idx < 288) {
      transp_tile_dev(Ts, w2, w2t, 768, 384, idx % 12, idx / 12);
    } else {
      int i2 = idx - 288;
      if (i2 < 144)
        transp_tile_dev(Ts, cw, Wct, 384, 384, i2 % 12, i2 / 12);
      else {
        int i3 = i2 - 144;
        transp_tile_dev(Ts, cw + 384 * 384, Wct + (size_t)384 * 384,
                        384, 384, i3 % 12, i3 / 12);
      }
    }
    return;
  }

  // ---- gemm1: K=768, N=768, nk=6
  const int m0 = (bid / 12) * 16, n0 = (bid % 12) * 64;
  const int lane = tid & 63, wave = tid >> 6;
  const int l15 = lane & 15, quad = lane >> 4, q8 = quad * 8;
  const int srA = tid >> 4, scA = (tid & 15) * 8;   // A: 16 rows x 16 thr x 8
  const int krB = tid >> 4, n4B = (tid & 15) * 4;   // B: 16 k-rows/pass x 16 thr x 4n
  f32x4 acc = splat4(0.f);

  float4 fb[8];
  bf16x8 ra;
  auto loadA = [&](int ko) {
    const float* Af = seq + (size_t)(m0 + srA) * 768 + scA + ko;
    float4 f0 = *(const float4*)(Af);
    float4 f1 = *(const float4*)(Af + 4);
    bf16x8 o;
    o[0] = (__bf16)f0.x; o[1] = (__bf16)f0.y; o[2] = (__bf16)f0.z; o[3] = (__bf16)f0.w;
    o[4] = (__bf16)f1.x; o[5] = (__bf16)f1.y; o[6] = (__bf16)f1.z; o[7] = (__bf16)f1.w;
    ra = o;
  };
  auto loadB = [&](int ko) {                    // coalesced: 16 lanes x 16B per k-row
    #pragma unroll
    for (int p = 0; p < 8; ++p)
      fb[p] = *(const float4*)(w1 + (size_t)(ko + p * 16 + krB) * 768 + n0 + n4B);
  };
  auto storeB = [&](int buf) {                  // transposed write: Bs[n][k]
    #pragma unroll
    for (int p = 0; p < 8; ++p) {
      int kl = p * 16 + krB;
      Bs[buf][n4B + 0][kl] = (__bf16)fb[p].x;
      Bs[buf][n4B + 1][kl] = (__bf16)fb[p].y;
      Bs[buf][n4B + 2][kl] = (__bf16)fb[p].z;
      Bs[buf][n4B + 3][kl] = (__bf16)fb[p].w;
    }
  };
  loadA(0);
  loadB(0);

  int buf = 0;
  for (int it = 0; it < 6; ++it) {
    *(bf16x8*)&As[buf][srA][scA] = ra;
    storeB(buf);
    __syncthreads();
    if (it + 1 < 6) {
      const int ko = (it + 1) * 128;
      loadA(ko);
      loadB(ko);
    }
    #pragma unroll
    for (int s = 0; s < 4; ++s) {
      bf16x8 a = *(const bf16x8*)&As[buf][l15][s * 32 + q8];
      bf16x8 b = *(const bf16x8*)&Bs[buf][wave * 16 + l15][s * 32 + q8];
      acc = __builtin_amdgcn_mfma_f32_16x16x32_bf16(a, b, acc, 0, 0, 0);
    }
    buf ^= 1;
  }
  const int col = n0 + wave * 16 + l15;
  const float bv = b1[col];
  #pragma unroll
  for (int r = 0; r < 4; ++r) {
    int row = m0 + quad * 4 + r;
    h1b[(size_t)row * 768 + col] = (__bf16)fmaxf(acc[r] + bv, 0.f);
  }
}

// ---------- bf16 MFMA GEMM, BM=16 x BN=64, 4 waves, BK=128 (R18 proven) -----
template<bool CVT_A, bool OUT_BF16, bool RELU, bool BIAS_LHALF>
__global__ __launch_bounds__(256) void gemm16_kernel(
    const void* __restrict__ Ain, const __bf16* __restrict__ Wt,
    const float* __restrict__ bias, void* __restrict__ out,
    int K, int N)
{
  __shared__ __align__(16) __bf16 As[2][16][136];
  __shared__ __align__(16) __bf16 Bs[2][64][136];
  const int tid = threadIdx.x;
  const int m0 = blockIdx.y * 16, n0 = blockIdx.x * 64;
  const int lane = tid & 63, wave = tid >> 6;
  const int l15 = lane & 15, quad = lane >> 4, q8 = quad * 8;
  const int srA = tid >> 4, scA = (tid & 15) * 8;
  const int srB = tid >> 2, scB = (tid & 3) * 32;
  f32x4 acc = splat4(0.f);

  const __bf16* Bptr = Wt + (size_t)(n0 + srB) * K + scB;
  bf16x8 ra, rb0, rb1, rb2, rb3;
  auto loadA = [&](int ko) {
    if constexpr (CVT_A) {
      const float* Af = (const float*)Ain + (size_t)(m0 + srA) * K + scA + ko;
      float4 f0 = *(const float4*)(Af);
      float4 f1 = *(const float4*)(Af + 4);
      bf16x8 o;
      o[0] = (__bf16)f0.x; o[1] = (__bf16)f0.y; o[2] = (__bf16)f0.z; o[3] = (__bf16)f0.w;
      o[4] = (__bf16)f1.x; o[5] = (__bf16)f1.y; o[6] = (__bf16)f1.z; o[7] = (__bf16)f1.w;
      ra = o;
    } else {
      ra = *(const bf16x8*)((const __bf16*)Ain + (size_t)(m0 + srA) * K + scA + ko);
    }
  };
  auto loadB = [&](int ko) {
    rb0 = *(const bf16x8*)(Bptr + ko);
    rb1 = *(const bf16x8*)(Bptr + ko + 8);
    rb2 = *(const bf16x8*)(Bptr + ko + 16);
    rb3 = *(const bf16x8*)(Bptr + ko + 24);
  };
  loadA(0);
  loadB(0);

  const int nk = K >> 7;
  int buf = 0;
  for (int it = 0; it < nk; ++it) {
    *(bf16x8*)&As[buf][srA][scA]      = ra;
    *(bf16x8*)&Bs[buf][srB][scB]      = rb0;
    *(bf16x8*)&Bs[buf][srB][scB + 8]  = rb1;
    *(bf16x8*)&Bs[buf][srB][scB + 16] = rb2;
    *(bf16x8*)&Bs[buf][srB][scB + 24] = rb3;
    __syncthreads();
    if (it + 1 < nk) {
      const int ko = (it + 1) * 128;
      loadA(ko);
      loadB(ko);
    }
    #pragma unroll
    for (int s = 0; s < 4; ++s) {
      bf16x8 a = *(const bf16x8*)&As[buf][l15][s * 32 + q8];
      bf16x8 b = *(const bf16x8*)&Bs[buf][wave * 16 + l15][s * 32 + q8];
      acc = __builtin_amdgcn_mfma_f32_16x16x32_bf16(a, b, acc, 0, 0, 0);
    }
    buf ^= 1;
  }
  const int col = n0 + wave * 16 + l15;
  float bv = 0.f;
  if (BIAS_LHALF) { if (col < HD) bv = bias[col]; }
  else if (bias)  bv = bias[col];
  #pragma unroll
  for (int r = 0; r < 4; ++r) {
    int row = m0 + quad * 4 + r;
    float v = acc[r] + bv;
    if (RELU) v = fmaxf(v, 0.f);
    if (OUT_BF16) ((__bf16*)out)[(size_t)row * N + col] = (__bf16)v;
    else          ((float*)out)[(size_t)row * N + col] = v;
  }
}

// ---------- fused head: 16x16 tiles, 8 waves, pk tanh, in-block Whead pack --
__global__ __launch_bounds__(512, 5) void fused_head_tile(
    const float* __restrict__ LR,
    const float* __restrict__ le_w, const float* __restrict__ le_b,
    const float* __restrict__ elh_w, const float* __restrict__ elh_b,
    const float* __restrict__ elt_w, const float* __restrict__ elt_b,
    const float* __restrict__ lgh_w, const float* __restrict__ lgh_b,
    const float* __restrict__ lgt_w, const float* __restrict__ lgt_b,
    float* __restrict__ out)
{
  __shared__ __align__(16) float Rs[16][388];
  __shared__ __align__(16) __bf16 Wl[6144];   // 12 KB fragment-packed Whead
  int x = blockIdx.x;
  int b = 0;
  if (x >= 528) { b = 1; x -= 528; }
  int ti = 0;
  while (x >= 32 - ti) { x -= 32 - ti; ++ti; }
  const int tj = ti + x;
  const int i0 = ti * 16, j0 = tj * 16;
  const int tid = threadIdx.x;

  const float* Rsrc = LR + (size_t)(b * S + j0) * (2 * HD) + HD;
  for (int t = tid; t < 1536; t += 512) {
    int row = t / 96, c4 = (t % 96) * 4;   // 16 rows x 384 f32
    *(f32x4*)&Rs[row][c4] = *(const f32x4*)(Rsrc + (size_t)row * (2 * HD) + c4);
  }
  if (tid < 384) {                        // in-block Whead fragment pack
    const int k = tid;
    float row[16];
    row[0] = le_w[k * 2 + 0];
    row[1] = le_w[k * 2 + 1];
    #pragma unroll
    for (int c = 0; c < 3; ++c) {
      row[2 + c]  = elh_w[k * 3 + c];
      row[5 + c]  = elt_w[k * 3 + c];
      row[8 + c]  = lgh_w[k * 3 + c];
      row[11 + c] = lgt_w[k * 3 + c];
    }
    row[14] = 0.f; row[15] = 0.f;
    int kk = k >> 5, qd = (k >> 3) & 3, e = k & 7;
    int base = ((kk * 4 + qd) * 16) * 8 + e;
    #pragma unroll
    for (int col = 0; col < 16; ++col)
      Wl[base + col * 8] = (__bf16)row[col];
  }
  const int lane = tid & 63, col = lane & 15, quad = lane >> 4;
  float bhv;
  {
    int c = col;
    bhv = (c < 2) ? le_b[c] : (c < 5) ? elh_b[c - 2] : (c < 8) ? elt_b[c - 5]
        : (c < 11) ? lgh_b[c - 8] : (c < 14) ? lgt_b[c - 11] : 0.f;
  }
  __syncthreads();

  const int wave = tid >> 6;            // 0..7; wave owns i-rows i, i+1
  const int i = i0 + wave * 2;
  const float* L0 = LR + (size_t)(b * S + i) * (2 * HD);
  const float* L1 = L0 + 2 * HD;
  f32x4 acc0 = splat4(0.f), acc1 = splat4(0.f);
  const int q8 = quad * 8;

  f32x4 a0[2], a1[2], c0[2], c1[2];
  a0[0] = *(const f32x4*)(L0 + q8);       a1[0] = *(const f32x4*)(L0 + q8 + 4);
  c0[0] = *(const f32x4*)(L1 + q8);       c1[0] = *(const f32x4*)(L1 + q8 + 4);
  a0[1] = *(const f32x4*)(L0 + 32 + q8);  a1[1] = *(const f32x4*)(L0 + 32 + q8 + 4);
  c0[1] = *(const f32x4*)(L1 + 32 + q8);  c1[1] = *(const f32x4*)(L1 + 32 + q8 + 4);
  f32x4 r0 = *(const f32x4*)&Rs[col][q8];
  f32x4 r1 = *(const f32x4*)&Rs[col][q8 + 4];

  #pragma unroll
  for (int kk = 0; kk < 12; ++kk) {
    const int p = kk & 1;
    f32x4 ta0 = a0[p], ta1 = a1[p], tc0 = c0[p], tc1 = c1[p];
    if (kk < 10) {
      const int kb2 = (kk + 2) * 32 + q8;
      a0[p] = *(const f32x4*)(L0 + kb2); a1[p] = *(const f32x4*)(L0 + kb2 + 4);
      c0[p] = *(const f32x4*)(L1 + kb2); c1[p] = *(const f32x4*)(L1 + kb2 + 4);
    }
    f32x4 tr0 = r0, tr1 = r1;
    if (kk < 11) {
      const int kb1 = (kk + 1) * 32 + q8;
      r0 = *(const f32x4*)&Rs[col][kb1];
      r1 = *(const f32x4*)&Rs[col][kb1 + 4];
    }
    bf16x8 w = *(const bf16x8*)&Wl[(size_t)((kk * 4 + quad) * 16 + col) * 8];
    f32x4 t0 = tanh4_pk(ta0, tr0);
    f32x4 t1 = tanh4_pk(ta1, tr1);
    bf16x8 af;
    af[0] = (__bf16)t0[0]; af[1] = (__bf16)t0[1];
    af[2] = (__bf16)t0[2]; af[3] = (__bf16)t0[3];
    af[4] = (__bf16)t1[0]; af[5] = (__bf16)t1[1];
    af[6] = (__bf16)t1[2]; af[7] = (__bf16)t1[3];
    acc0 = __builtin_amdgcn_mfma_f32_16x16x32_bf16(af, w, acc0, 0, 0, 0);
    t0 = tanh4_pk(tc0, tr0);
    t1 = tanh4_pk(tc1, tr1);
    bf16x8 ag;
    ag[0] = (__bf16)t0[0]; ag[1] = (__bf16)t0[1];
    ag[2] = (__bf16)t0[2]; ag[3] = (__bf16)t0[3];
    ag[4] = (__bf16)t1[0]; ag[5] = (__bf16)t1[1];
    ag[6] = (__bf16)t1[2]; ag[7] = (__bf16)t1[3];
    acc1 = __builtin_amdgcn_mfma_f32_16x16x32_bf16(ag, w, acc1, 0, 0, 0);
  }
  if (col < NOUT) {
    #pragma unroll
    for (int ii = 0; ii < 2; ++ii) {
      const int ic = i + ii;
      const f32x4 acc = ii ? acc1 : acc0;
      const size_t pbase = (size_t)b * NPAIR + (size_t)ic * S - ((size_t)ic * (ic - 1)) / 2;
      #pragma unroll
      for (int r = 0; r < 4; ++r) {
        int j = j0 + quad * 4 + r;
        if (j >= ic)
          out[(pbase + (size_t)(j - ic)) * NOUT + col] = acc[r] + bhv;
      }
    }
  }
}

extern "C" void kernel_launch(void* const* d_in, const int* in_sizes, int n_in,
                              void* d_out, int out_size, void* d_ws, size_t ws_size,
                              hipStream_t stream) {
  const float* seq   = (const float*)d_in[0];
  const float* w1    = (const float*)d_in[1];
  const float* b1    = (const float*)d_in[2];
  const float* w2    = (const float*)d_in[3];
  const float* b2    = (const float*)d_in[4];
  const float* cw    = (const float*)d_in[5];
  const float* cbp   = (const float*)d_in[6];
  const float* le_w  = (const float*)d_in[7];
  const float* le_b  = (const float*)d_in[8];
  const float* elh_w = (const float*)d_in[9];
  const float* elh_b = (const float*)d_in[10];
  const float* elt_w = (const float*)d_in[11];
  const float* elt_b = (const float*)d_in[12];
  const float* lgh_w = (const float*)d_in[13];
  const float* lgh_b = (const float*)d_in[14];
  const float* lgt_w = (const float*)d_in[15];
  const float* lgt_b = (const float*)d_in[16];

  char* p = (char*)d_ws;
  float*  LRb = (float*)p;                   // 3,145,728 B  [L|R] f32, +cb on L
  __bf16* h1b = (__bf16*)(p + 1572864);      // overlaps LRb (dead before gemm3)
  __bf16* h2b = (__bf16*)(p + 3145728);      //   786,432 B
  __bf16* w2t = (__bf16*)(p + 3932160);      //   589,824 B
  __bf16* Wct = (__bf16*)(p + 4521984);      //   589,824 B  (total 5.11 MB)

  // 1) gemm1 (transposes w1 in-staging) + w2t/Wct transposes in spare blocks
  gemm1_prep_kernel<<<1344, 256, 0, stream>>>(seq, w1, b1, h1b, w2, w2t, cw, Wct);
  // 2) h2 = relu(h1 @ w2 + b2)
  gemm16_kernel<false, true, true, false><<<dim3(6, 64), 256, 0, stream>>>(
      h1b, w2t, b2, h2b, 768, 384);
  // 3) LR = h2 @ [w_top|w_bot] (+cb on L)
  gemm16_kernel<false, false, false, true><<<dim3(12, 64), 256, 0, stream>>>(
      h2b, Wct, cbp, LRb, 384, 768);
  // 4) fused pair-head (packs Whead in-block)
  fused_head_tile<<<1056, 512, 0, stream>>>(
      LRb, le_w, le_b, elh_w, elh_b, elt_w, elt_b,
      lgh_w, lgh_b, lgt_w, lgt_b, (float*)d_out);
}

// Round 20
// 53.569 us; speedup vs baseline: 1.1854x; 1.1854x over previous
//
#include <hip/hip_runtime.h>
#include <hip/hip_bf16.h>

#define S 512
#define HD 384
#define NPAIR 131328   // S*(S+1)/2
#define NOUT 14

typedef __bf16 bf16x8 __attribute__((ext_vector_type(8)));
typedef _Float16 f16x8 __attribute__((ext_vector_type(8)));
typedef float f32x4 __attribute__((ext_vector_type(4)));

__device__ __forceinline__ f32x4 splat4(float v) { return f32x4{v, v, v, v}; }
__device__ __forceinline__ f16x8 splat8h(float v) {
  _Float16 h = (_Float16)v;
  return f16x8{h, h, h, h, h, h, h, h};
}

// tanh(l+r) for 8 elements, deg-5 odd fit (same coeffs as R11; add in f32,
// poly in PACKED f16 -> v_pk_fma_f16 full-rate dual issue). f16 quantization
// (2^-11) is 8x finer than the bf16 A-operand it replaces -> accuracy improves.
__device__ __forceinline__ f16x8 tanh8_h(f32x4 l0, f32x4 r0, f32x4 l1, f32x4 r1) {
  f32x4 x0 = l0 + r0, x1 = l1 + r1;
  f16x8 x = {(_Float16)x0[0], (_Float16)x0[1], (_Float16)x0[2], (_Float16)x0[3],
             (_Float16)x1[0], (_Float16)x1[1], (_Float16)x1[2], (_Float16)x1[3]};
  f16x8 u = x * x;
  f16x8 p = __builtin_elementwise_fma(u, splat8h(0.065750f), splat8h(-0.303330f));
  p = __builtin_elementwise_fma(u, p, splat8h(0.997245f));
  return x * p;
}

// ---------- prep: weight transposes + head-weight fragment pack (f16) -------
__device__ __forceinline__ void transp_tile(
    const float* __restrict__ src, __bf16* __restrict__ dst,
    int R, int C, int bx, int by)
{
  __shared__ float t[32][33];
  const int tx = threadIdx.x & 31, ty = threadIdx.x >> 5;  // 32 x 8
  const int c = bx * 32 + tx;
  #pragma unroll
  for (int p = 0; p < 4; ++p) {
    int r = by * 32 + ty + p * 8;
    t[ty + p * 8][tx] = src[(size_t)r * C + c];
  }
  __syncthreads();
  #pragma unroll
  for (int p = 0; p < 4; ++p) {
    int cc = bx * 32 + ty + p * 8;
    int rr = by * 32 + tx;
    dst[(size_t)cc * R + rr] = (__bf16)t[tx][ty + p * 8];
  }
}

__global__ __launch_bounds__(256) void prep_all_kernel(
    const float* __restrict__ w1, __bf16* __restrict__ w1t,
    const float* __restrict__ w2, __bf16* __restrict__ w2t,
    const float* __restrict__ cw, __bf16* __restrict__ Wct,
    const float* __restrict__ le_w, const float* __restrict__ le_b,
    const float* __restrict__ elh_w, const float* __restrict__ elh_b,
    const float* __restrict__ elt_w, const float* __restrict__ elt_b,
    const float* __restrict__ lgh_w, const float* __restrict__ lgh_b,
    const float* __restrict__ lgt_w, const float* __restrict__ lgt_b,
    _Float16* __restrict__ Whb, float* __restrict__ bh)
{
  const int bid = blockIdx.x;
  if (bid < 576) {
    transp_tile(w1, w1t, 768, 768, bid % 24, bid / 24);
  } else if (bid < 864) {
    int idx = bid - 576;
    transp_tile(w2, w2t, 768, 384, idx % 12, idx / 12);
  } else if (bid < 1008) {
    int idx = bid - 864;
    transp_tile(cw, Wct, 384, 384, idx % 12, idx / 12);
  } else if (bid < 1152) {
    int idx = bid - 1008;
    transp_tile(cw + 384 * 384, Wct + (size_t)384 * 384, 384, 384, idx % 12, idx / 12);
  } else {
    for (int k = threadIdx.x; k < 384; k += 256) {
      float row[16];
      row[0] = le_w[k * 2 + 0];
      row[1] = le_w[k * 2 + 1];
      #pragma unroll
      for (int c = 0; c < 3; ++c) {
        row[2 + c]  = elh_w[k * 3 + c];
        row[5 + c]  = elt_w[k * 3 + c];
        row[8 + c]  = lgh_w[k * 3 + c];
        row[11 + c] = lgt_w[k * 3 + c];
      }
      row[14] = 0.f; row[15] = 0.f;
      int kk = k >> 5, quad = (k >> 3) & 3, e = k & 7;
      size_t base = (size_t)((kk * 4 + quad) * 16) * 8 + e;
      #pragma unroll
      for (int col = 0; col < 16; ++col)
        Whb[base + col * 8] = (_Float16)row[col];
      if (k < 16) {
        float v = 0.f;
        if (k < 2) v = le_b[k];
        else if (k < 5) v = elh_b[k - 2];
        else if (k < 8) v = elt_b[k - 5];
        else if (k < 11) v = lgh_b[k - 8];
        else if (k < 14) v = lgt_b[k - 11];
        bh[k] = v;
      }
    }
  }
}

// ---------- bf16 MFMA GEMM, BM=16 x BN=64, 4 waves, BK=128 (R18 proven) -----
template<bool CVT_A, bool OUT_BF16, bool RELU, bool BIAS_LHALF>
__global__ __launch_bounds__(256) void gemm16_kernel(
    const void* __restrict__ Ain, const __bf16* __restrict__ Wt,
    const float* __restrict__ bias, void* __restrict__ out,
    int K, int N)
{
  __shared__ __align__(16) __bf16 As[2][16][136];   //  8.7 KB
  __shared__ __align__(16) __bf16 Bs[2][64][136];   // 34.8 KB
  const int tid = threadIdx.x;
  const int m0 = blockIdx.y * 16, n0 = blockIdx.x * 64;
  const int lane = tid & 63, wave = tid >> 6;
  const int l15 = lane & 15, quad = lane >> 4, q8 = quad * 8;
  const int srA = tid >> 4, scA = (tid & 15) * 8;   // 16 rows x 16 thr x 8 bf16
  const int srB = tid >> 2, scB = (tid & 3) * 32;   // 64 rows x 4 thr x 32 bf16
  f32x4 acc = splat4(0.f);

  const __bf16* Bptr = Wt + (size_t)(n0 + srB) * K + scB;
  bf16x8 ra, rb0, rb1, rb2, rb3;
  auto loadA = [&](int ko) {
    if constexpr (CVT_A) {
      const float* Af = (const float*)Ain + (size_t)(m0 + srA) * K + scA + ko;
      float4 f0 = *(const float4*)(Af);
      float4 f1 = *(const float4*)(Af + 4);
      bf16x8 o;
      o[0] = (__bf16)f0.x; o[1] = (__bf16)f0.y; o[2] = (__bf16)f0.z; o[3] = (__bf16)f0.w;
      o[4] = (__bf16)f1.x; o[5] = (__bf16)f1.y; o[6] = (__bf16)f1.z; o[7] = (__bf16)f1.w;
      ra = o;
    } else {
      ra = *(const bf16x8*)((const __bf16*)Ain + (size_t)(m0 + srA) * K + scA + ko);
    }
  };
  auto loadB = [&](int ko) {
    rb0 = *(const bf16x8*)(Bptr + ko);
    rb1 = *(const bf16x8*)(Bptr + ko + 8);
    rb2 = *(const bf16x8*)(Bptr + ko + 16);
    rb3 = *(const bf16x8*)(Bptr + ko + 24);
  };
  loadA(0);
  loadB(0);

  const int nk = K >> 7;   // K multiple of 128
  int buf = 0;
  for (int it = 0; it < nk; ++it) {
    *(bf16x8*)&As[buf][srA][scA]      = ra;
    *(bf16x8*)&Bs[buf][srB][scB]      = rb0;
    *(bf16x8*)&Bs[buf][srB][scB + 8]  = rb1;
    *(bf16x8*)&Bs[buf][srB][scB + 16] = rb2;
    *(bf16x8*)&Bs[buf][srB][scB + 24] = rb3;
    __syncthreads();
    if (it + 1 < nk) {
      const int ko = (it + 1) * 128;
      loadA(ko);
      loadB(ko);
    }
    #pragma unroll
    for (int s = 0; s < 4; ++s) {
      bf16x8 a = *(const bf16x8*)&As[buf][l15][s * 32 + q8];
      bf16x8 b = *(const bf16x8*)&Bs[buf][wave * 16 + l15][s * 32 + q8];
      acc = __builtin_amdgcn_mfma_f32_16x16x32_bf16(a, b, acc, 0, 0, 0);
    }
    buf ^= 1;
  }
  const int col = n0 + wave * 16 + l15;
  float bv = 0.f;
  if (BIAS_LHALF) { if (col < HD) bv = bias[col]; }
  else if (bias)  bv = bias[col];
  #pragma unroll
  for (int r = 0; r < 4; ++r) {
    int row = m0 + quad * 4 + r;
    float v = acc[r] + bv;
    if (RELU) v = fmaxf(v, 0.f);
    if (OUT_BF16) ((__bf16*)out)[(size_t)row * N + col] = (__bf16)v;
    else          ((float*)out)[(size_t)row * N + col] = v;
  }
}

// ---------- fused head: 16x16 tiles, 8 waves, f16 poly + f16 MFMA -----------
__global__ __launch_bounds__(512, 5) void fused_head_tile(
    const float* __restrict__ LR, const _Float16* __restrict__ Whb,
    const float* __restrict__ bh, float* __restrict__ out)
{
  __shared__ __align__(16) float Rs[16][388];
  __shared__ __align__(16) _Float16 Wl[6144];   // 12 KB = 768 f16x8 chunks
  int x = blockIdx.x;
  int b = 0;
  if (x >= 528) { b = 1; x -= 528; }
  int ti = 0;
  while (x >= 32 - ti) { x -= 32 - ti; ++ti; }
  const int tj = ti + x;
  const int i0 = ti * 16, j0 = tj * 16;
  const int tid = threadIdx.x;

  const float* Rsrc = LR + (size_t)(b * S + j0) * (2 * HD) + HD;
  for (int t = tid; t < 1536; t += 512) {
    int row = t / 96, c4 = (t % 96) * 4;   // 16 rows x 384 f32
    *(f32x4*)&Rs[row][c4] = *(const f32x4*)(Rsrc + (size_t)row * (2 * HD) + c4);
  }
  for (int t = tid; t < 768; t += 512)
    ((f16x8*)Wl)[t] = ((const f16x8*)Whb)[t];
  const int lane = tid & 63, col = lane & 15, quad = lane >> 4;
  const float bhv = bh[col];
  __syncthreads();

  const int wave = tid >> 6;            // 0..7; wave owns i-rows i, i+1
  const int i = i0 + wave * 2;
  const float* L0 = LR + (size_t)(b * S + i) * (2 * HD);
  const float* L1 = L0 + 2 * HD;
  f32x4 acc0 = splat4(0.f), acc1 = splat4(0.f);
  const int q8 = quad * 8;

  // depth-2 L (global) prefetch, depth-1 R (LDS) — structure proven R17/R18
  f32x4 a0[2], a1[2], c0[2], c1[2];
  a0[0] = *(const f32x4*)(L0 + q8);       a1[0] = *(const f32x4*)(L0 + q8 + 4);
  c0[0] = *(const f32x4*)(L1 + q8);       c1[0] = *(const f32x4*)(L1 + q8 + 4);
  a0[1] = *(const f32x4*)(L0 + 32 + q8);  a1[1] = *(const f32x4*)(L0 + 32 + q8 + 4);
  c0[1] = *(const f32x4*)(L1 + 32 + q8);  c1[1] = *(const f32x4*)(L1 + 32 + q8 + 4);
  f32x4 r0 = *(const f32x4*)&Rs[col][q8];
  f32x4 r1 = *(const f32x4*)&Rs[col][q8 + 4];

  #pragma unroll
  for (int kk = 0; kk < 12; ++kk) {
    const int p = kk & 1;                // compile-time per unrolled iter
    f32x4 ta0 = a0[p], ta1 = a1[p], tc0 = c0[p], tc1 = c1[p];
    if (kk < 10) {
      const int kb2 = (kk + 2) * 32 + q8;
      a0[p] = *(const f32x4*)(L0 + kb2); a1[p] = *(const f32x4*)(L0 + kb2 + 4);
      c0[p] = *(const f32x4*)(L1 + kb2); c1[p] = *(const f32x4*)(L1 + kb2 + 4);
    }
    f32x4 tr0 = r0, tr1 = r1;
    if (kk < 11) {
      const int kb1 = (kk + 1) * 32 + q8;
      r0 = *(const f32x4*)&Rs[col][kb1];
      r1 = *(const f32x4*)&Rs[col][kb1 + 4];
    }
    f16x8 w = *(const f16x8*)&Wl[(size_t)((kk * 4 + quad) * 16 + col) * 8];
    f16x8 af = tanh8_h(ta0, tr0, ta1, tr1);
    acc0 = __builtin_amdgcn_mfma_f32_16x16x32_f16(af, w, acc0, 0, 0, 0);
    f16x8 ag = tanh8_h(tc0, tr0, tc1, tr1);
    acc1 = __builtin_amdgcn_mfma_f32_16x16x32_f16(ag, w, acc1, 0, 0, 0);
  }
  if (col < NOUT) {
    #pragma unroll
    for (int ii = 0; ii < 2; ++ii) {
      const int ic = i + ii;
      const f32x4 acc = ii ? acc1 : acc0;
      const size_t pbase = (size_t)b * NPAIR + (size_t)ic * S - ((size_t)ic * (ic - 1)) / 2;
      #pragma unroll
      for (int r = 0; r < 4; ++r) {
        int j = j0 + quad * 4 + r;
        if (j >= ic)
          out[(pbase + (size_t)(j - ic)) * NOUT + col] = acc[r] + bhv;
      }
    }
  }
}

extern "C" void kernel_launch(void* const* d_in, const int* in_sizes, int n_in,
                              void* d_out, int out_size, void* d_ws, size_t ws_size,
                              hipStream_t stream) {
  const float* seq   = (const float*)d_in[0];
  const float* w1    = (const float*)d_in[1];
  const float* b1    = (const float*)d_in[2];
  const float* w2    = (const float*)d_in[3];
  const float* b2    = (const float*)d_in[4];
  const float* cw    = (const float*)d_in[5];
  const float* cbp   = (const float*)d_in[6];
  const float* le_w  = (const float*)d_in[7];
  const float* le_b  = (const float*)d_in[8];
  const float* elh_w = (const float*)d_in[9];
  const float* elh_b = (const float*)d_in[10];
  const float* elt_w = (const float*)d_in[11];
  const float* elt_b = (const float*)d_in[12];
  const float* lgh_w = (const float*)d_in[13];
  const float* lgh_b = (const float*)d_in[14];
  const float* lgt_w = (const float*)d_in[15];
  const float* lgt_b = (const float*)d_in[16];

  char* p = (char*)d_ws;
  float*    LRb = (float*)p;                 // 3,145,728 B  [L|R] f32, +cb on L
  __bf16*   h1b = (__bf16*)(p + 1572864);    // overlaps LRb (dead before gemm3)
  __bf16*   h2b = (__bf16*)(p + 3145728);    //   786,432 B
  __bf16*   w1t = (__bf16*)(p + 3932160);    // 1,179,648 B
  __bf16*   w2t = (__bf16*)(p + 5111808);    //   589,824 B
  __bf16*   Wct = (__bf16*)(p + 5701632);    //   589,824 B
  float*    bh  = (float*)(p + 6291456);     //        64 B
  _Float16* Whb = (_Float16*)(p + 6291520);  //    12,288 B

  prep_all_kernel<<<1153, 256, 0, stream>>>(
      w1, w1t, w2, w2t, cw, Wct,
      le_w, le_b, elh_w, elh_b, elt_w, elt_b,
      lgh_w, lgh_b, lgt_w, lgt_b, Whb, bh);
  // h1 = relu(seq @ w1 + b1); 768 blocks
  gemm16_kernel<true, true, true, false><<<dim3(12, 64), 256, 0, stream>>>(
      seq, w1t, b1, h1b, 768, 768);
  // h2 = relu(h1 @ w2 + b2); 384 blocks
  gemm16_kernel<false, true, true, false><<<dim3(6, 64), 256, 0, stream>>>(
      h1b, w2t, b2, h2b, 768, 384);
  // LR = h2 @ [w_top|w_bot] (+cb on L); 768 blocks
  gemm16_kernel<false, false, false, true><<<dim3(12, 64), 256, 0, stream>>>(
      h2b, Wct, cbp, LRb, 384, 768);
  fused_head_tile<<<1056, 512, 0, stream>>>(LRb, Whb, bh, (float*)d_out);
}